// Round 8
// baseline (72.713 us; speedup 1.0000x reference)
//
#include <hip/hip_runtime.h>
#include <hip/hip_bf16.h>

typedef float f32x4 __attribute__((ext_vector_type(4)));
typedef int   i32x4 __attribute__((ext_vector_type(4)));
typedef int   i32x8 __attribute__((ext_vector_type(8)));

#define NC 4096
#define ND 1024
#define EPSF 1e-10f
#define NT 8        // K-tiles of BK=128 (fp8)
#define SCALE1 127  // E8M0 exponent byte for 2^0

// Fragment-tiled fp8 layout (per matrix, 4 MB):
//   addr(row,k) = (((kt*256 + R16)*2 + half)*64 + hi*16 + lo)*16 + b
//   kt=k>>7, hi=(k&127)>>5, half=(k&31)>>4, b=k&15, R16=row>>4, lo=row&15.
// A wave's MFMA operand for (kt, R16) is 2 KB: lane L reads 16 B at
// frag+L*16 and 16 B at frag+1024+L*16 — two fully-coalesced dwordx4.
// Per-lane content (row=lo, k=hi*32+[0,32)) identical to the LDS path
// proven correct in rounds 3-7.

// ---------------- fp32 -> fp8 e4m3 convert (frag-tiled) + row norms/sums ----------------
__global__ void convert_kernel(const float* __restrict__ F, const float* __restrict__ P,
                               unsigned char* __restrict__ Fb, unsigned char* __restrict__ Pb,
                               float* __restrict__ f2, float* __restrict__ p2,
                               float* __restrict__ psum,
                               const int* __restrict__ ann, int n_ann,
                               float* __restrict__ counts, float* __restrict__ accum) {
  int bid = blockIdx.x;
  int tid = threadIdx.x;
  if (bid == 2 * NC) {  // fused mask/zero block (no atomics: LDS bitmap)
    __shared__ unsigned char mark[NC];
    for (int i = tid; i < NC; i += 256) mark[i] = 0;
    __syncthreads();
    for (int t = tid; t < n_ann; t += 256) {
      int idx = ann[t * 5 + 4];
      if (idx >= 0 && idx < NC) mark[idx] = 1;  // benign race: all write 1
    }
    __syncthreads();
    for (int i = tid; i < NC; i += 256) counts[i] = (float)mark[i];
    if (tid < 8) accum[tid] = 0.f;   // re-zero every call (graph replay)
    return;
  }
  bool isP = bid >= NC;
  int row = isP ? bid - NC : bid;
  const float* src = (isP ? P : F) + (size_t)row * ND;
  unsigned char* dst = isP ? Pb : Fb;
  float4 v = *reinterpret_cast<const float4*>(src + tid * 4);
  int pk = __builtin_amdgcn_cvt_pk_fp8_f32(v.x, v.y, 0, false);   // bytes 0,1
  pk = __builtin_amdgcn_cvt_pk_fp8_f32(v.z, v.w, pk, true);       // bytes 2,3
  {
    int d0 = tid * 4;
    int kt = d0 >> 7, hi = (d0 >> 5) & 3, half = (d0 >> 4) & 1, b = d0 & 15;
    int R16 = row >> 4, lo = row & 15;
    size_t fa = ((((size_t)kt * 256 + R16) * 2 + half) * 64 + hi * 16 + lo) * 16 + b;
    *reinterpret_cast<int*>(dst + fa) = pk;
  }
  float sq = v.x * v.x + v.y * v.y + v.z * v.z + v.w * v.w;
  float sm = v.x + v.y + v.z + v.w;
  #pragma unroll
  for (int off = 32; off; off >>= 1) {
    sq += __shfl_down(sq, off);
    sm += __shfl_down(sm, off);
  }
  __shared__ float rs[4], rm[4];
  int wid = tid >> 6, lane = tid & 63;
  if (lane == 0) { rs[wid] = sq; rm[wid] = sm; }
  __syncthreads();
  if (tid == 0) {
    float tsq = rs[0] + rs[1] + rs[2] + rs[3];
    float tsm = rm[0] + rm[1] + rm[2] + rm[3];
    if (isP) { p2[row] = tsq; psum[row] = tsm; }
    else     { f2[row] = tsq; }
  }
}

// ---------------- barrier-free frag-direct MX-fp8 GEMM + loss reduction ----------------
// Load the wave's 4 A-frags and 4 B-frags of K-tile kt straight to VGPRs.
#define LOADAB(AV, BV, kt)                                                    \
  do {                                                                        \
    _Pragma("unroll")                                                         \
    for (int _m = 0; _m < 4; ++_m) {                                          \
      const unsigned char* _p =                                               \
          Fb + (size_t)((kt) * 256 + wA4 + _m) * 2048 + lane * 16;            \
      i32x4 _l0 = *(const i32x4*)(_p);                                        \
      i32x4 _l1 = *(const i32x4*)(_p + 1024);                                 \
      AV[_m] = __builtin_shufflevector(_l0, _l1, 0, 1, 2, 3, 4, 5, 6, 7);     \
      const unsigned char* _q =                                               \
          Pb + (size_t)((kt) * 256 + wB4 + _m) * 2048 + lane * 16;            \
      i32x4 _r0 = *(const i32x4*)(_q);                                        \
      i32x4 _r1 = *(const i32x4*)(_q + 1024);                                 \
      BV[_m] = __builtin_shufflevector(_r0, _r1, 0, 1, 2, 3, 4, 5, 6, 7);     \
    }                                                                         \
  } while (0)

#define MFMA16(AV, BV)                                                        \
  do {                                                                        \
    __builtin_amdgcn_s_setprio(1);                                            \
    _Pragma("unroll")                                                         \
    for (int _m = 0; _m < 4; ++_m)                                            \
      _Pragma("unroll")                                                       \
      for (int _n = 0; _n < 4; ++_n)                                          \
        acc[_m][_n] = __builtin_amdgcn_mfma_scale_f32_16x16x128_f8f6f4(       \
            AV[_m], BV[_n], acc[_m][_n], 0 /*A=fp8*/, 0 /*B=fp8*/,            \
            0, SCALE1, 0, SCALE1);                                            \
    __builtin_amdgcn_s_setprio(0);                                            \
  } while (0)

__global__ __launch_bounds__(256, 2)   // VGPR cap 256; 8 waves/CU
void gemm_loss_kernel(const unsigned char* __restrict__ Fb,
                      const unsigned char* __restrict__ Pb,
                      const float* __restrict__ f2, const float* __restrict__ p2,
                      const float* __restrict__ counts, const float* __restrict__ psum,
                      float* accum) {
  __shared__ float redI[4], redE[4];

  // 2-D slab XCD swizzle (round-7 proven): per-XCD working set 3 MB < L2.
  const int xcd = blockIdx.x & 7;
  const int s = blockIdx.x >> 3;                  // 0..127 within slab
  const int bi = (xcd >> 1) * 8 + (s >> 4);       // 4 slab-rows of 8
  const int bj = (xcd & 1) * 16 + (s & 15);       // 2 slab-cols of 16

  const int tid = threadIdx.x;
  const int lane = tid & 63, wid = tid >> 6;
  const int wr = wid >> 1, wc = wid & 1;  // 2x2 wave grid, 64x64 each
  const int lo = lane & 15, hi = lane >> 4;

  const int wA4 = (bi * 2 + wr) * 4;  // first A R16-frag of this wave
  const int wB4 = (bj * 2 + wc) * 4;  // first B R16-frag of this wave

  f32x4 acc[4][4];
  f32x4 zero = {0.f, 0.f, 0.f, 0.f};
  #pragma unroll
  for (int m = 0; m < 4; ++m)
    #pragma unroll
    for (int n = 0; n < 4; ++n) acc[m][n] = zero;

  // Barrier-free ping-pong K-loop: frags of kt+1 load (global->VGPR,
  // compiler-counted vmcnt) while MFMAs of kt run. No LDS, no s_barrier,
  // no lockstep: waves pipeline independently, TLP hides L2 latency.
  i32x8 a0[4], b0[4], a1[4], b1[4];
  LOADAB(a0, b0, 0);
  #pragma unroll 1
  for (int kt = 0; kt < NT; kt += 2) {
    LOADAB(a1, b1, kt + 1);
    MFMA16(a0, b0);
    if (kt + 2 < NT) LOADAB(a0, b0, kt + 2);
    MFMA16(a1, b1);
  }

  // Epilogue: per-element msd -> intra (diag) / inter (off-diag) partials.
  // C/D layout (shape-determined): col = lane&15, row = (lane>>4)*4 + reg.
  float intra_l = 0.f, inter_l = 0.f;
  const int gi0 = bi * 128 + wr * 64 + hi * 4;
  const int gj0 = bj * 128 + wc * 64 + lo;
  float f2i[16];
  int mi[16];
  #pragma unroll
  for (int m = 0; m < 4; ++m)
    #pragma unroll
    for (int r = 0; r < 4; ++r) {
      int gi = gi0 + m * 16 + r;
      f2i[m * 4 + r] = f2[gi];
      mi[m * 4 + r] = counts[gi] > 0.f;
    }
  #pragma unroll
  for (int n = 0; n < 4; ++n) {
    int gj = gj0 + n * 16;
    float p2j = p2[gj];
    bool mj = psum[gj] != 0.f;
    if (mj) {
      #pragma unroll
      for (int m = 0; m < 4; ++m) {
        #pragma unroll
        for (int r = 0; r < 4; ++r) {
          if (!mi[m * 4 + r]) continue;
          int gi = gi0 + m * 16 + r;
          float cij = acc[m][n][r];
          float msd = fmaxf(f2i[m * 4 + r] + p2j - 2.f * cij, 0.f) * (1.f / 1024.f);
          if (gi == gj) {
            intra_l += msd;                 // diagonal: intra
          } else if (msd < 1.0f) {          // inter term nonzero only if sqrt(msd)<1
            float s = sqrtf(fmaxf(msd, 1e-12f));
            float e = 1.f - s;
            float e2 = e * e;
            inter_l += e2 * e2;             // (e/M)^2 * max(e,0)^2, M=1
          }
        }
      }
    }
  }
  #pragma unroll
  for (int off = 32; off; off >>= 1) {
    intra_l += __shfl_down(intra_l, off);
    inter_l += __shfl_down(inter_l, off);
  }
  if (lane == 0) { redI[wid] = intra_l; redE[wid] = inter_l; }
  __syncthreads();
  if (tid == 0) {
    atomicAdd(&accum[0], redI[0] + redI[1] + redI[2] + redI[3]);
    atomicAdd(&accum[1], redE[0] + redE[1] + redE[2] + redE[3]);
  }
}

// ---------------- mask counts + finalize (fused) ----------------
__global__ void finalize_kernel(const float* __restrict__ counts,
                                const float* __restrict__ psum,
                                const float* __restrict__ accum,
                                float* __restrict__ out) {
  int tid = threadIdx.x;
  int ni = 0, nj = 0, nd = 0;
  for (int i = tid; i < NC; i += 256) {
    int mi = counts[i] > 0.f;
    int mj = psum[i] != 0.f;
    ni += mi; nj += mj; nd += (mi & mj);
  }
  #pragma unroll
  for (int off = 32; off; off >>= 1) {
    ni += __shfl_down(ni, off);
    nj += __shfl_down(nj, off);
    nd += __shfl_down(nd, off);
  }
  __shared__ int r0[4], r1[4], r2[4];
  int wid = tid >> 6, lane = tid & 63;
  if (lane == 0) { r0[wid] = ni; r1[wid] = nj; r2[wid] = nd; }
  __syncthreads();
  if (tid == 0) {
    float fni = (float)(r0[0] + r0[1] + r0[2] + r0[3]);
    float fnj = (float)(r1[0] + r1[1] + r1[2] + r1[3]);
    float fnd = (float)(r2[0] + r2[1] + r2[2] + r2[3]);
    out[0] = accum[0] / (fnd + EPSF);
    out[1] = accum[1] / (fni * fnj - fnd + EPSF);
  }
}

extern "C" void kernel_launch(void* const* d_in, const int* in_sizes, int n_in,
                              void* d_out, int out_size, void* d_ws, size_t ws_size,
                              hipStream_t stream) {
  const float* F = (const float*)d_in[0];
  const float* P = (const float*)d_in[1];
  const int* ann = (const int*)d_in[2];
  int n_ann = in_sizes[2] / 5;

  char* ws = (char*)d_ws;
  unsigned char* Fb = (unsigned char*)ws;                          // 4 MB (frag-tiled)
  unsigned char* Pb = (unsigned char*)(ws + (size_t)NC * ND);      // 4 MB (frag-tiled)
  float* f2     = (float*)(ws + (size_t)NC * ND * 2);
  float* p2     = f2 + NC;
  float* psum   = p2 + NC;
  float* counts = psum + NC;
  float* accum  = counts + NC;  // [0]=intra_sum [1]=inter_sum

  float* out = (float*)d_out;

  convert_kernel<<<2 * NC + 1, 256, 0, stream>>>(F, P, Fb, Pb, f2, p2, psum,
                                                 ann, n_ann, counts, accum);
  gemm_loss_kernel<<<(NC / 128) * (NC / 128), 256, 0, stream>>>(Fb, Pb, f2, p2, counts, psum, accum);
  finalize_kernel<<<1, 256, 0, stream>>>(counts, psum, accum, out);
}

// Round 9
// 34.561 us; speedup vs baseline: 2.1039x; 2.1039x over previous
//
#include <hip/hip_runtime.h>
#include <hip/hip_bf16.h>

typedef float f32x4 __attribute__((ext_vector_type(4)));
typedef int   i32x4 __attribute__((ext_vector_type(4)));
typedef int   i32x8 __attribute__((ext_vector_type(8)));

#define NC 4096
#define ND 1024
#define NVP 256     // padded compact-row count (B*A = 256 annotations max)
#define EPSF 1e-10f
#define NT 8        // K-tiles of BK=128 (fp8)
#define SCALE1 127  // E8M0 exponent byte for 2^0

// Fragment-tiled fp8 layout (round-8 verified):
//   frag id = kt*NR16 + R16 (NR16 = rows/16), frag = 2048 B.
//   Within frag: byte = half*1024 + lane*16 + b, where lane=(hi*16+lo),
//   row = R16*16+lo, k = kt*128 + hi*32 + half*16 + b.
//   A wave's operand load = two coalesced dwordx4 at lane*16 and +1024.

// ---------------- mask + deterministic compact + zero accum (1 block) ----------------
__global__ void mask_compact_kernel(const int* __restrict__ ann, int n_ann,
                                    float* __restrict__ counts,
                                    int* __restrict__ vidx, int* __restrict__ nv,
                                    float* __restrict__ accum) {
  __shared__ unsigned char mark[NC];
  __shared__ int wsum[4];
  int tid = threadIdx.x;
  for (int i = tid; i < NC; i += 256) mark[i] = 0;
  __syncthreads();
  for (int t = tid; t < n_ann; t += 256) {
    int idx = ann[t * 5 + 4];
    if (idx >= 0 && idx < NC) mark[idx] = 1;  // benign race: all write 1
  }
  __syncthreads();
  for (int i = tid; i < NC; i += 256) counts[i] = (float)mark[i];
  // deterministic compaction: thread t owns classes [t*16, t*16+16)
  int base = tid * 16, lc = 0;
  #pragma unroll
  for (int k = 0; k < 16; ++k) lc += mark[base + k];
  int lane = tid & 63, wid = tid >> 6;
  int inc = lc;
  #pragma unroll
  for (int off = 1; off < 64; off <<= 1) {
    int v = __shfl_up(inc, off);
    if (lane >= off) inc += v;
  }
  if (lane == 63) wsum[wid] = inc;
  __syncthreads();
  int wbase = 0;
  for (int w = 0; w < wid; ++w) wbase += wsum[w];
  int pos = wbase + inc - lc;   // exclusive prefix
  for (int k = 0; k < 16; ++k)
    if (mark[base + k]) vidx[pos++] = base + k;
  int total = wsum[0] + wsum[1] + wsum[2] + wsum[3];
  if (tid == 0) *nv = total;
  for (int i = total + tid; i < NVP; i += 256) vidx[i] = 0;  // padded rows
  if (tid < 8) accum[tid] = 0.f;  // re-zero every call (graph replay)
}

// ---------------- fp32 -> fp8 convert (frag-tiled): P rows + compact F rows ----------------
__global__ void convert_kernel(const float* __restrict__ F, const float* __restrict__ P,
                               unsigned char* __restrict__ Fc, unsigned char* __restrict__ Pb,
                               float* __restrict__ f2c, float* __restrict__ p2,
                               float* __restrict__ psum,
                               const int* __restrict__ vidx, const int* __restrict__ nv) {
  int bid = blockIdx.x;
  int tid = threadIdx.x;
  bool isP = bid < NC;
  float4 v = {0.f, 0.f, 0.f, 0.f};
  int orow = 0;  // output row index within the frag-tiled buffer
  if (isP) {
    orow = bid;
    v = *reinterpret_cast<const float4*>(P + (size_t)orow * ND + tid * 4);
  } else {
    int ci = bid - NC;           // 0..255 compact slot
    orow = ci;
    if (ci < *nv) {
      int row = vidx[ci];
      v = *reinterpret_cast<const float4*>(F + (size_t)row * ND + tid * 4);
    }                            // else stays zero (padded row -> zero frags)
  }
  int pk = __builtin_amdgcn_cvt_pk_fp8_f32(v.x, v.y, 0, false);   // bytes 0,1
  pk = __builtin_amdgcn_cvt_pk_fp8_f32(v.z, v.w, pk, true);       // bytes 2,3
  {
    int d0 = tid * 4;
    int kt = d0 >> 7, hi = (d0 >> 5) & 3, half = (d0 >> 4) & 1, b = d0 & 15;
    int R16 = orow >> 4, lo = orow & 15;
    int nr16 = isP ? NC / 16 : NVP / 16;
    unsigned char* dst = isP ? Pb : Fc;
    size_t fa = ((((size_t)kt * nr16 + R16) * 2 + half) * 64 + hi * 16 + lo) * 16 + b;
    *reinterpret_cast<int*>(dst + fa) = pk;
  }
  float sq = v.x * v.x + v.y * v.y + v.z * v.z + v.w * v.w;
  float sm = v.x + v.y + v.z + v.w;
  #pragma unroll
  for (int off = 32; off; off >>= 1) {
    sq += __shfl_down(sq, off);
    sm += __shfl_down(sm, off);
  }
  __shared__ float rs[4], rm[4];
  int wid = tid >> 6, lane = tid & 63;
  if (lane == 0) { rs[wid] = sq; rm[wid] = sm; }
  __syncthreads();
  if (tid == 0) {
    float tsq = rs[0] + rs[1] + rs[2] + rs[3];
    float tsm = rm[0] + rm[1] + rm[2] + rm[3];
    if (isP) { p2[orow] = tsq; psum[orow] = tsm; }
    else     { f2c[orow] = tsq; }
  }
}

// ---------------- masked 256x4096 frag-direct MX-fp8 GEMM + loss ----------------
#define LDFRAG(V, BASEPTR, FID)                                               \
  do {                                                                        \
    const unsigned char* _p = (BASEPTR) + (size_t)(FID) * 2048 + lane * 16;   \
    i32x4 _l0 = *(const i32x4*)(_p);                                          \
    i32x4 _l1 = *(const i32x4*)(_p + 1024);                                   \
    V = __builtin_shufflevector(_l0, _l1, 0, 1, 2, 3, 4, 5, 6, 7);            \
  } while (0)

#define MFMA4(AV, BV)                                                         \
  do {                                                                        \
    _Pragma("unroll")                                                         \
    for (int _m = 0; _m < 2; ++_m)                                            \
      _Pragma("unroll")                                                       \
      for (int _n = 0; _n < 2; ++_n)                                          \
        acc[_m][_n] = __builtin_amdgcn_mfma_scale_f32_16x16x128_f8f6f4(       \
            AV[_m], BV[_n], acc[_m][_n], 0 /*A=fp8*/, 0 /*B=fp8*/,            \
            0, SCALE1, 0, SCALE1);                                            \
  } while (0)

__global__ __launch_bounds__(256)
void gemm_loss_kernel(const unsigned char* __restrict__ Fc,
                      const unsigned char* __restrict__ Pb,
                      const float* __restrict__ f2c, const float* __restrict__ p2,
                      const float* __restrict__ psum, const int* __restrict__ vidx,
                      const int* __restrict__ nv, float* __restrict__ accum) {
  __shared__ float redI[4], redE[4];
  const int bi = blockIdx.x >> 6;   // 0..3   (M-tiles of 64 compact rows)
  const int bj = blockIdx.x & 63;   // 0..63  (N-tiles of 64 cols)
  const int tid = threadIdx.x;
  const int lane = tid & 63, wid = tid >> 6;
  const int wr = wid >> 1, wc = wid & 1;  // 2x2 wave grid, 32x32 each
  const int lo = lane & 15, hi = lane >> 4;
  const int ra = bi * 4 + wr * 2;   // A R16 base (0..15)
  const int rb = bj * 4 + wc * 2;   // B R16 base (0..255)

  f32x4 acc[2][2];
  f32x4 zero = {0.f, 0.f, 0.f, 0.f};
  #pragma unroll
  for (int m = 0; m < 2; ++m)
    #pragma unroll
    for (int n = 0; n < 2; ++n) acc[m][n] = zero;

  // Barrier-free ping-pong over NT=8 K-tiles; 4 frags live per set
  // (acc 16 + operands 64 + addr regs -> no spill).
  i32x8 a0[2], b0[2], a1[2], b1[2];
  LDFRAG(a0[0], Fc, 0 * 16 + ra);  LDFRAG(a0[1], Fc, 0 * 16 + ra + 1);
  LDFRAG(b0[0], Pb, 0 * 256 + rb); LDFRAG(b0[1], Pb, 0 * 256 + rb + 1);
  #pragma unroll 1
  for (int kt = 0; kt < NT; kt += 2) {
    LDFRAG(a1[0], Fc, (kt + 1) * 16 + ra);  LDFRAG(a1[1], Fc, (kt + 1) * 16 + ra + 1);
    LDFRAG(b1[0], Pb, (kt + 1) * 256 + rb); LDFRAG(b1[1], Pb, (kt + 1) * 256 + rb + 1);
    MFMA4(a0, b0);
    if (kt + 2 < NT) {
      LDFRAG(a0[0], Fc, (kt + 2) * 16 + ra);  LDFRAG(a0[1], Fc, (kt + 2) * 16 + ra + 1);
      LDFRAG(b0[0], Pb, (kt + 2) * 256 + rb); LDFRAG(b0[1], Pb, (kt + 2) * 256 + rb + 1);
    }
    MFMA4(a1, b1);
  }

  // Epilogue. C/D layout: col = lane&15, row = (lane>>4)*4 + reg.
  // Row mask = (ci < Nv); diagonal when vidx[ci] == gj.
  int Nv = *nv;
  float intra_l = 0.f, inter_l = 0.f;
  const int ci0 = bi * 64 + wr * 32 + hi * 4;
  const int gj0 = bj * 64 + wc * 32 + lo;
  #pragma unroll
  for (int n = 0; n < 2; ++n) {
    int gj = gj0 + n * 16;
    float p2j = p2[gj];
    bool mj = psum[gj] != 0.f;
    if (mj) {
      #pragma unroll
      for (int m = 0; m < 2; ++m) {
        #pragma unroll
        for (int r = 0; r < 4; ++r) {
          int ci = ci0 + m * 16 + r;
          if (ci >= Nv) continue;
          float cij = acc[m][n][r];
          float msd = fmaxf(f2c[ci] + p2j - 2.f * cij, 0.f) * (1.f / 1024.f);
          int gi = vidx[ci];
          if (gi == gj) {
            intra_l += msd;                 // diagonal: intra
          } else if (msd < 1.0f) {          // inter term nonzero only if sqrt(msd)<1
            float s = sqrtf(fmaxf(msd, 1e-12f));
            float e = 1.f - s;
            float e2 = e * e;
            inter_l += e2 * e2;             // (e/M)^2 * max(e,0)^2, M=1
          }
        }
      }
    }
  }
  #pragma unroll
  for (int off = 32; off; off >>= 1) {
    intra_l += __shfl_down(intra_l, off);
    inter_l += __shfl_down(inter_l, off);
  }
  if (lane == 0) { redI[wid] = intra_l; redE[wid] = inter_l; }
  __syncthreads();
  if (tid == 0) {
    atomicAdd(&accum[0], redI[0] + redI[1] + redI[2] + redI[3]);
    atomicAdd(&accum[1], redE[0] + redE[1] + redE[2] + redE[3]);
  }
}

// ---------------- mask counts + finalize (fused) ----------------
__global__ void finalize_kernel(const float* __restrict__ counts,
                                const float* __restrict__ psum,
                                const float* __restrict__ accum,
                                float* __restrict__ out) {
  int tid = threadIdx.x;
  int ni = 0, nj = 0, nd = 0;
  for (int i = tid; i < NC; i += 256) {
    int mi = counts[i] > 0.f;
    int mj = psum[i] != 0.f;
    ni += mi; nj += mj; nd += (mi & mj);
  }
  #pragma unroll
  for (int off = 32; off; off >>= 1) {
    ni += __shfl_down(ni, off);
    nj += __shfl_down(nj, off);
    nd += __shfl_down(nd, off);
  }
  __shared__ int r0[4], r1[4], r2[4];
  int wid = tid >> 6, lane = tid & 63;
  if (lane == 0) { r0[wid] = ni; r1[wid] = nj; r2[wid] = nd; }
  __syncthreads();
  if (tid == 0) {
    float fni = (float)(r0[0] + r0[1] + r0[2] + r0[3]);
    float fnj = (float)(r1[0] + r1[1] + r1[2] + r1[3]);
    float fnd = (float)(r2[0] + r2[1] + r2[2] + r2[3]);
    out[0] = accum[0] / (fnd + EPSF);
    out[1] = accum[1] / (fni * fnj - fnd + EPSF);
  }
}

extern "C" void kernel_launch(void* const* d_in, const int* in_sizes, int n_in,
                              void* d_out, int out_size, void* d_ws, size_t ws_size,
                              hipStream_t stream) {
  const float* F = (const float*)d_in[0];
  const float* P = (const float*)d_in[1];
  const int* ann = (const int*)d_in[2];
  int n_ann = in_sizes[2] / 5;

  char* ws = (char*)d_ws;
  unsigned char* Pb = (unsigned char*)ws;                              // 4 MB frag-tiled
  unsigned char* Fc = (unsigned char*)(ws + (size_t)NC * ND);          // 256 KB frag-tiled
  float* p2     = (float*)(ws + (size_t)NC * ND + (size_t)NVP * ND);
  float* psum   = p2 + NC;
  float* counts = psum + NC;
  float* f2c    = counts + NC;
  float* accum  = f2c + NVP;    // [0]=intra_sum [1]=inter_sum
  int*   vidx   = (int*)(accum + 8);
  int*   nv     = vidx + NVP;

  float* out = (float*)d_out;

  mask_compact_kernel<<<1, 256, 0, stream>>>(ann, n_ann, counts, vidx, nv, accum);
  convert_kernel<<<NC + NVP, 256, 0, stream>>>(F, P, Fc, Pb, f2c, p2, psum, vidx, nv);
  gemm_loss_kernel<<<4 * 64, 256, 0, stream>>>(Fc, Pb, f2c, p2, psum, vidx, nv, accum);
  finalize_kernel<<<1, 256, 0, stream>>>(counts, psum, accum, out);
}